// Round 2
// baseline (1119.872 us; speedup 1.0000x reference)
//
#include <hip/hip_runtime.h>
#include <hip/hip_bf16.h>
#include <cstdint>
#include <cstddef>

typedef __attribute__((ext_vector_type(8))) short short8;
typedef __attribute__((ext_vector_type(4))) float floatx4;

#define BM 128
#define BN 128
#define BK 32

// fp32 -> bf16 round-to-nearest-even
__device__ __forceinline__ ushort f2bf(float f) {
  uint32_t u = __builtin_bit_cast(uint32_t, f);
  u += 0x7FFFu + ((u >> 16) & 1u);
  return (ushort)(u >> 16);
}

// ---------------- head: [N,3] logits -> log_softmax -> ws ----------------
__global__ void head_kernel(const float* __restrict__ x,
                            const float* __restrict__ hw,
                            float* __restrict__ head_lp, int K) {
  const int row = blockIdx.x;
  const int lane = threadIdx.x;  // 64 threads
  const float* xr = x + (size_t)row * K;
  float d0 = 0.f, d1 = 0.f, d2 = 0.f;
  for (int k = lane; k < K; k += 64) {
    float xv = xr[k];
    d0 = fmaf(xv, hw[k], d0);
    d1 = fmaf(xv, hw[K + k], d1);
    d2 = fmaf(xv, hw[2 * K + k], d2);
  }
#pragma unroll
  for (int off = 32; off > 0; off >>= 1) {
    d0 += __shfl_down(d0, off);
    d1 += __shfl_down(d1, off);
    d2 += __shfl_down(d2, off);
  }
  if (lane == 0) {
    float m = fmaxf(d0, fmaxf(d1, d2));
    float s = expf(d0 - m) + expf(d1 - m) + expf(d2 - m);
    float lse = m + logf(s);
    head_lp[row * 3 + 0] = d0 - lse;
    head_lp[row * 3 + 1] = d1 - lse;
    head_lp[row * 3 + 2] = d2 - lse;
  }
}

// ---------------- GEMM: out[n, v] = X[n,:] . W[v,:]  (bf16 MFMA) ----------------
// W is the virtual concat of W0,W1,W2 (row-major [Vi, K]).
__global__ __launch_bounds__(256) void gemm_kernel(
    const float* __restrict__ X, const float* __restrict__ W0,
    const float* __restrict__ W1, const float* __restrict__ W2,
    float* __restrict__ out, int K, int V0, int V01, int V) {
  __shared__ ushort As[BM * BK];
  __shared__ ushort Bs[BN * BK];

  const int tid = threadIdx.x;
  const int lane = tid & 63;
  const int w = tid >> 6;
  const int wm = w >> 1, wn = w & 1;      // 2x2 wave grid, 64x64 each
  const int bm0 = blockIdx.x * BM;
  const int bn0 = blockIdx.y * BN;

  floatx4 acc[4][4];
#pragma unroll
  for (int i = 0; i < 4; ++i)
#pragma unroll
    for (int j = 0; j < 4; ++j) acc[i][j] = (floatx4){0.f, 0.f, 0.f, 0.f};

  const int r0 = tid >> 3;        // 0..31
  const int kg = (tid & 7) * 4;   // 0,4,..,28

  for (int k0 = 0; k0 < K; k0 += BK) {
    __syncthreads();
    // stage A (X) and B (W) tiles, fp32 -> bf16, XOR-swizzled LDS
#pragma unroll
    for (int p = 0; p < 4; ++p) {
      const int row = r0 + p * 32;  // 0..127
      // A
      float4 av = *(const float4*)(X + (size_t)(bm0 + row) * K + k0 + kg);
      union { ushort u[4]; uint2 d; } Pa;
      Pa.u[0] = f2bf(av.x); Pa.u[1] = f2bf(av.y);
      Pa.u[2] = f2bf(av.z); Pa.u[3] = f2bf(av.w);
      *(uint2*)&As[row * BK + (kg ^ ((row & 3) << 3))] = Pa.d;
      // B: pick W row for this vocab index
      int vg = bn0 + row;
      int vc = vg < V ? vg : V - 1;
      const float* wrow = (vc < V0)  ? (W0 + (size_t)vc * K)
                        : (vc < V01) ? (W1 + (size_t)(vc - V0) * K)
                                     : (W2 + (size_t)(vc - V01) * K);
      float4 bv = *(const float4*)(wrow + k0 + kg);
      union { ushort u[4]; uint2 d; } Pb;
      Pb.u[0] = f2bf(bv.x); Pb.u[1] = f2bf(bv.y);
      Pb.u[2] = f2bf(bv.z); Pb.u[3] = f2bf(bv.w);
      *(uint2*)&Bs[row * BK + (kg ^ ((row & 3) << 3))] = Pb.d;
    }
    __syncthreads();

    short8 af[4], bf[4];
    const int kfr = (lane >> 4) * 8;  // k-group of 8
#pragma unroll
    for (int mi = 0; mi < 4; ++mi) {
      const int row = wm * 64 + mi * 16 + (lane & 15);
      af[mi] = *(const short8*)&As[row * BK + (kfr ^ ((row & 3) << 3))];
      const int col = wn * 64 + mi * 16 + (lane & 15);
      bf[mi] = *(const short8*)&Bs[col * BK + (kfr ^ ((col & 3) << 3))];
    }
#pragma unroll
    for (int mi = 0; mi < 4; ++mi)
#pragma unroll
      for (int ni = 0; ni < 4; ++ni)
        acc[mi][ni] = __builtin_amdgcn_mfma_f32_16x16x32_bf16(
            af[mi], bf[ni], acc[mi][ni], 0, 0, 0);
  }

  // epilogue: C[row][col], col = lane&15, row = (lane>>4)*4 + r
#pragma unroll
  for (int mi = 0; mi < 4; ++mi) {
    const int row = bm0 + wm * 64 + mi * 16 + ((lane >> 4) << 2);
#pragma unroll
    for (int ni = 0; ni < 4; ++ni) {
      const int col = bn0 + wn * 64 + ni * 16 + (lane & 15);
      if (col < V) {
#pragma unroll
        for (int r = 0; r < 4; ++r)
          out[(size_t)(row + r) * V + col] = acc[mi][ni][r];
      }
    }
  }
}

// ---------------- per-(row, cluster) log_softmax, in place ----------------
__global__ __launch_bounds__(1024) void lsm_kernel(
    float* __restrict__ out, const float* __restrict__ head_lp,
    int V, int V0, int V1, int V2) {
  const int c = blockIdx.x;    // cluster
  const int row = blockIdx.y;  // token
  const int off = (c == 0) ? 0 : (c == 1) ? V0 : V0 + V1;
  const int size = (c == 0) ? V0 : (c == 1) ? V1 : V2;
  float* ptr = out + (size_t)row * V + off;
  const int tid = threadIdx.x;

  float v[20];
  float tmax = -INFINITY;
#pragma unroll
  for (int j = 0; j < 20; ++j) {
    int i = tid + j * 1024;
    v[j] = (i < size) ? ptr[i] : -INFINITY;
    tmax = fmaxf(tmax, v[j]);
  }

  __shared__ float red[18];
#pragma unroll
  for (int o = 32; o > 0; o >>= 1) tmax = fmaxf(tmax, __shfl_xor(tmax, o));
  const int wid = tid >> 6;
  const int lane = tid & 63;
  if (lane == 0) red[wid] = tmax;
  __syncthreads();
  if (tid == 0) {
    float m = red[0];
#pragma unroll
    for (int i = 1; i < 16; ++i) m = fmaxf(m, red[i]);
    red[16] = m;
  }
  __syncthreads();
  const float M = red[16];

  float s = 0.f;
#pragma unroll
  for (int j = 0; j < 20; ++j) s += __expf(v[j] - M);  // -inf -> 0
#pragma unroll
  for (int o = 32; o > 0; o >>= 1) s += __shfl_xor(s, o);
  if (lane == 0) red[wid] = s;
  __syncthreads();
  if (tid == 0) {
    float t = 0.f;
#pragma unroll
    for (int i = 0; i < 16; ++i) t += red[i];
    red[17] = t;
  }
  __syncthreads();
  const float S = red[17];

  const float hlp = head_lp[row * 3 + c];
  const float sub = M + logf(S) - hlp;
#pragma unroll
  for (int j = 0; j < 20; ++j) {
    int i = tid + j * 1024;
    if (i < size) ptr[i] = v[j] - sub;
  }
}

extern "C" void kernel_launch(void* const* d_in, const int* in_sizes, int n_in,
                              void* d_out, int out_size, void* d_ws, size_t ws_size,
                              hipStream_t stream) {
  const float* x  = (const float*)d_in[0];
  const float* hw = (const float*)d_in[1];
  const float* w0 = (const float*)d_in[2];
  const float* w1 = (const float*)d_in[3];
  const float* w2 = (const float*)d_in[4];
  float* out = (float*)d_out;

  const int d  = in_sizes[1] / 3;     // 1024
  const int N  = in_sizes[0] / d;     // 2048
  const int V0 = in_sizes[2] / d;     // 20000
  const int V1 = in_sizes[3] / d;     // 20000
  const int V2 = in_sizes[4] / d;     // 10257
  const int V  = V0 + V1 + V2;        // 50257

  float* head_lp = (float*)d_ws;      // N*3 floats

  head_kernel<<<N, 64, 0, stream>>>(x, hw, head_lp, d);

  dim3 grid((N + BM - 1) / BM, (V + BN - 1) / BN);
  gemm_kernel<<<grid, 256, 0, stream>>>(x, w0, w1, w2, out, d, V0, V0 + V1, V);

  lsm_kernel<<<dim3(3, N), 1024, 0, stream>>>(out, head_lp, V, V0, V1, V2);
}